// Round 3
// baseline (1000.354 us; speedup 1.0000x reference)
//
#include <hip/hip_runtime.h>
#include <stdint.h>

// TBNN fused, split-bf16 (hi+lo) 3-pass MFMA for fp32-grade accuracy.
// prep kernel: pre-splits weights into bf16 hi/lo, pre-swizzled LDS images in d_ws.
// main kernel: 512 thr (8 waves, 2/SIMD for MFMA<->VALU overlap), each wave owns
// 64 points end-to-end; h stays in registers (cvt_pk + permlane32_swap converts
// MFMA C-layout -> B-layout, hi & lo). Weights roll through a 2x64KB LDS ring via
// global_load_lds. s_setprio(1) around MFMA clusters (T5). 5 barriers/tile.

#define NPTS   1000000
#define TPB    512
#define NBLKS  256
#define NT     ((NPTS + 511) / 512)

typedef uint32_t u32;
typedef __attribute__((ext_vector_type(4)))  u32   u32x4;
typedef __attribute__((ext_vector_type(8)))  short s16x8;
typedef __attribute__((ext_vector_type(16))) float f32x16;
typedef __attribute__((ext_vector_type(4), aligned(4))) float f32x4u;

// ---- workspace layout (prep output, exact LDS images) ----
#define WS_L(s)   ((s)*65536)              // hidden layers 2..5: 128 rows x 512B ([hi 256|lo 256], XOR-swizzled)
#define WS_TAIL   262144                   // heads + W1 + bias, staged as one 16KB block
#define WS_HEADS  262144                   // 16 rows x 512B
#define WS_W1     (262144 + 8192)          // 128 rows x 32B: [Wh(5),b,Wl(5),Wh(5)]
#define WS_BIAS   (262144 + 8192 + 4096)   // [4][128] hidden biases + [32] head biases (bf16)

// ---- LDS layout ----
#define LDS_BUF0   0
#define LDS_BUF1   65536
#define LDS_HEADS  131072
#define LDS_W1     (131072 + 8192)
#define LDS_BIAS   (131072 + 8192 + 4096)
#define LDS_TOTAL  147456

#define MFMA(a,b,c) __builtin_amdgcn_mfma_f32_32x32x16_bf16((a),(b),(c),0,0,0)
#define BC16(v)     __builtin_bit_cast(s16x8, (v))

__device__ __forceinline__ u32 cvtpk(float lo, float hi) {
    u32 r;
    asm("v_cvt_pk_bf16_f32 %0, %1, %2" : "=v"(r) : "v"(lo), "v"(hi));
    return r;
}
__device__ __forceinline__ float lo2f(u32 p){ return __builtin_bit_cast(float, p << 16); }
__device__ __forceinline__ float hi2f(u32 p){ return __builtin_bit_cast(float, p & 0xffff0000u); }
__device__ __forceinline__ uint16_t f2bf(float f) {   // RNE fp32->bf16
    u32 u = __builtin_bit_cast(u32, f);
    return (uint16_t)((u + 0x7fffu + ((u >> 16) & 1u)) >> 16);
}
__device__ __forceinline__ float b2f(uint16_t h){ return __builtin_bit_cast(float, (u32)h << 16); }

// cooperative global->LDS DMA: 512 threads x 16B = 8KB per iteration, linear image copy
__device__ __forceinline__ void stageN(const char* g, char* l, int tid, int nbytes) {
    const int w = tid >> 6, ln = tid & 63;
    const char* gp = g + w*1024 + ln*16;
    char* lp = l + w*1024;                 // wave-uniform LDS base (lane offset is HW-implicit)
    #pragma unroll
    for (int i = 0; i < 8; ++i) {
        if (i*8192 >= nbytes) break;
        __builtin_amdgcn_global_load_lds(
            (const __attribute__((address_space(1))) uint32_t*)(gp + i*8192),
            (__attribute__((address_space(3))) uint32_t*)(lp + i*8192),
            16, 0, 0);
    }
}

// ---------------- prep: split + swizzle weights into ws ----------------
extern "C" __global__ void __launch_bounds__(256)
tbnn_prep(const float* __restrict__ W1, const float* __restrict__ b1,
          const float* __restrict__ W2, const float* __restrict__ b2,
          const float* __restrict__ W3, const float* __restrict__ b3,
          const float* __restrict__ W4, const float* __restrict__ b4,
          const float* __restrict__ W5, const float* __restrict__ b5,
          const float* __restrict__ Wc, const float* __restrict__ bc,
          const float* __restrict__ Wg1,const float* __restrict__ bg1,
          const float* __restrict__ Wg2,const float* __restrict__ bg2,
          const float* __restrict__ Wg3,const float* __restrict__ bg3,
          char* __restrict__ ws)
{
    int idx = blockIdx.x*256 + threadIdx.x;
    if (idx < 65536) {                         // hidden layers 2..5
        int l = idx >> 14, r = idx & 16383, ifc = r >> 7, of = r & 127;
        const float* Wt = (l==0)?W2:(l==1)?W3:(l==2)?W4:W5;
        float w = Wt[ifc*128 + of];
        uint16_t hb = f2bf(w);
        uint16_t lb = f2bf(w - b2f(hb));
        char* row = ws + WS_L(l) + of*512;
        int o = (2*ifc) ^ ((of&7)<<4);         // closed within [0,256)
        *(uint16_t*)(row + o)       = hb;
        *(uint16_t*)(row + 256 + o) = lb;
    } else if (idx < 65536 + 2048) {           // heads: rows 0..9 Wc, 10..12 Wg, 13..15 zero
        int j = idx - 65536, of = j >> 7, ifc = j & 127;
        float v = 0.f;
        if      (of < 10)  v = Wc[ifc*10 + of];
        else if (of == 10) v = Wg1[ifc];
        else if (of == 11) v = Wg2[ifc];
        else if (of == 12) v = Wg3[ifc];
        uint16_t hb = f2bf(v);
        uint16_t lb = f2bf(v - b2f(hb));
        char* row = ws + WS_HEADS + of*512;
        int o = (2*ifc) ^ ((of&7)<<4);
        *(uint16_t*)(row + o)       = hb;
        *(uint16_t*)(row + 256 + o) = lb;
    } else if (idx < 65536 + 2048 + 128) {     // W1 rows: [Wh(5), b, Wl(5), Wh(5)]
        int of = idx - (65536 + 2048);
        uint16_t* dst = (uint16_t*)(ws + WS_W1 + of*32);
        #pragma unroll
        for (int s = 0; s < 5; ++s) {
            float w = W1[s*128 + of];
            uint16_t hb = f2bf(w);
            dst[s]      = hb;
            dst[6 + s]  = f2bf(w - b2f(hb));
            dst[11 + s] = hb;
        }
        dst[5] = f2bf(b1[of]);
    } else if (idx < 65536 + 2048 + 128 + 544) { // bias arrays (bf16)
        int j = idx - (65536 + 2048 + 128);
        float v = 0.f;
        if (j < 512) {
            int l = j >> 7, of = j & 127;
            const float* bt = (l==0)?b2:(l==1)?b3:(l==2)?b4:b5;
            v = bt[of];
        } else {
            int of = j - 512;
            if      (of < 10)  v = bc[of];
            else if (of == 10) v = bg1[0];
            else if (of == 11) v = bg2[0];
            else if (of == 12) v = bg3[0];
        }
        *(uint16_t*)(ws + WS_BIAS + j*2) = f2bf(v);
    }
}

// ---------------- main ----------------
extern "C" __global__ void __launch_bounds__(TPB, 2)
tbnn_main(const float* __restrict__ x, const float* __restrict__ tb,
          const char* __restrict__ ws, float* __restrict__ out)
{
    extern __shared__ char smem[];
    const int tid  = threadIdx.x;
    const int wave = tid >> 6;
    const int lane = tid & 63;
    const int col  = lane & 31;
    const int hi   = lane >> 5;
    const int sm   = (col & 7) << 4;   // read-side swizzle (row&7 == col&7)
    const int hib  = hi * 16;          // byte offset: hi half reads k-slots 8..15

    // initial stages: L2->buf0, L3->buf1, tail (heads+W1+bias)
    stageN(ws + WS_L(0), smem + LDS_BUF0, tid, 65536);
    stageN(ws + WS_L(1), smem + LDS_BUF1, tid, 65536);
    stageN(ws + WS_TAIL, smem + LDS_HEADS, tid, 16384);
    __syncthreads();

    u32x4 Bc; Bc[0] = hi ? 0u : 0x00003F80u; Bc[1]=0u; Bc[2]=0u; Bc[3]=0u; // bias k-step B (1.0 at k=0)
    f32x16 zf;
    #pragma unroll
    for (int i = 0; i < 16; ++i) zf[i] = 0.f;

    for (int t = blockIdx.x; t < NT; t += gridDim.x) {
        const int pb = t*512 + wave*64;

        f32x16 acc[4][2];
        u32x4  Bh[2][8], Bl[2][8];

        // MFMA C-layout -> next-layer B fragments (hi + lo), relu fused
        auto convert = [&]() {
            #pragma unroll
            for (int pt = 0; pt < 2; ++pt)
            #pragma unroll
            for (int ot = 0; ot < 4; ++ot) {
                f32x16 a = acc[ot][pt];
                #pragma unroll
                for (int h2 = 0; h2 < 2; ++h2) {
                    float e0 = fmaxf(a[8*h2+0], 0.f), e1 = fmaxf(a[8*h2+1], 0.f);
                    float e2 = fmaxf(a[8*h2+2], 0.f), e3 = fmaxf(a[8*h2+3], 0.f);
                    float e4 = fmaxf(a[8*h2+4], 0.f), e5 = fmaxf(a[8*h2+5], 0.f);
                    float e6 = fmaxf(a[8*h2+6], 0.f), e7 = fmaxf(a[8*h2+7], 0.f);
                    u32 h01 = cvtpk(e0,e1), h23 = cvtpk(e2,e3);
                    u32 h45 = cvtpk(e4,e5), h67 = cvtpk(e6,e7);
                    u32 l01 = cvtpk(e0 - lo2f(h01), e1 - hi2f(h01));
                    u32 l23 = cvtpk(e2 - lo2f(h23), e3 - hi2f(h23));
                    u32 l45 = cvtpk(e4 - lo2f(h45), e5 - hi2f(h45));
                    u32 l67 = cvtpk(e6 - lo2f(h67), e7 - hi2f(h67));
                    auto sh1 = __builtin_amdgcn_permlane32_swap(h01, h45, false, false);
                    auto sh2 = __builtin_amdgcn_permlane32_swap(h23, h67, false, false);
                    u32x4 fh; fh[0]=sh1[0]; fh[1]=sh2[0]; fh[2]=sh1[1]; fh[3]=sh2[1];
                    Bh[pt][2*ot+h2] = fh;
                    auto sl1 = __builtin_amdgcn_permlane32_swap(l01, l45, false, false);
                    auto sl2 = __builtin_amdgcn_permlane32_swap(l23, l67, false, false);
                    u32x4 fl; fl[0]=sl1[0]; fl[1]=sl2[0]; fl[2]=sl1[1]; fl[3]=sl2[1];
                    Bl[pt][2*ot+h2] = fl;
                }
            }
        };

        { // ---- L1: one K=16 step packs Wh*xh + b + Wl*xh + Wh*xl ----
            u32x4 Bx[2];
            #pragma unroll
            for (int pt = 0; pt < 2; ++pt) {
                int p = pb + pt*32 + col;
                float x0=0.f,x1=0.f,x2=0.f,x3=0.f,x4=0.f;
                if (p < NPTS) {
                    const float* xp = x + (size_t)p*5;
                    f32x4u v = *(const f32x4u*)xp;
                    x0=v.x; x1=v.y; x2=v.z; x3=v.w; x4=xp[4];
                }
                float h0 = lo2f(cvtpk(x0,x0)), l0 = x0 - h0;
                float h1 = lo2f(cvtpk(x1,x1)), l1 = x1 - h1;
                float h2 = lo2f(cvtpk(x2,x2)), l2 = x2 - h2;
                float h3 = lo2f(cvtpk(x3,x3)), l3 = x3 - h3;
                float h4 = lo2f(cvtpk(x4,x4)), l4 = x4 - h4;
                u32x4 B;
                if (hi == 0) {   // k0..7 : [xh0..4, 1, xh0, xh1]
                    B[0] = cvtpk(h0,h1); B[1] = cvtpk(h2,h3);
                    B[2] = cvtpk(h4,1.0f); B[3] = cvtpk(h0,h1);
                } else {         // k8..15: [xh2,xh3,xh4, xl0..4]
                    B[0] = cvtpk(h2,h3); B[1] = cvtpk(h4,l0);
                    B[2] = cvtpk(l1,l2); B[3] = cvtpk(l3,l4);
                }
                Bx[pt] = B;
            }
            __builtin_amdgcn_s_setprio(1);
            #pragma unroll
            for (int ot = 0; ot < 4; ++ot) {
                u32x4 Av = *(const u32x4*)(smem + LDS_W1 + (ot*32+col)*32 + hib);
                s16x8 a = BC16(Av);
                acc[ot][0] = MFMA(a, BC16(Bx[0]), zf);
                acc[ot][1] = MFMA(a, BC16(Bx[1]), zf);
            }
            __builtin_amdgcn_s_setprio(0);
        }
        convert();
        __syncthreads();   // drains rolling stages issued last iteration

        // ---- hidden layers 2..5 (ring: layer l uses buf l&1) ----
        for (int l = 0; l < 4; ++l) {
            const char* wb = smem + (size_t)(l & 1)*65536;
            __builtin_amdgcn_s_setprio(1);
            // P3: Wh * Al  (consumes Bl)
            #pragma unroll
            for (int k = 0; k < 8; ++k)
            #pragma unroll
            for (int ot = 0; ot < 4; ++ot) {
                u32x4 Av = *(const u32x4*)(wb + (ot*32+col)*512 + ((k*32 + hib) ^ sm));
                s16x8 a = BC16(Av);
                acc[ot][0] = MFMA(a, BC16(Bl[0][k]), (k==0) ? zf : acc[ot][0]);
                acc[ot][1] = MFMA(a, BC16(Bl[1][k]), (k==0) ? zf : acc[ot][1]);
            }
            // P1+P2: Wh*Ah + Wl*Ah
            #pragma unroll
            for (int k = 0; k < 8; ++k)
            #pragma unroll
            for (int ot = 0; ot < 4; ++ot) {
                const char* rp = wb + (ot*32+col)*512;
                int so = (k*32 + hib) ^ sm;
                u32x4 AvH = *(const u32x4*)(rp + so);
                u32x4 AvL = *(const u32x4*)(rp + 256 + so);
                acc[ot][0] = MFMA(BC16(AvH), BC16(Bh[0][k]), acc[ot][0]);
                acc[ot][1] = MFMA(BC16(AvH), BC16(Bh[1][k]), acc[ot][1]);
                acc[ot][0] = MFMA(BC16(AvL), BC16(Bh[0][k]), acc[ot][0]);
                acc[ot][1] = MFMA(BC16(AvL), BC16(Bh[1][k]), acc[ot][1]);
            }
            // bias k-step: A = bias column (k_local 0), B = Bc
            #pragma unroll
            for (int ot = 0; ot < 4; ++ot) {
                u32 bw = (u32)*(const uint16_t*)(smem + LDS_BIAS + (l*128 + ot*32 + col)*2);
                u32x4 Ab; Ab[0] = hi ? 0u : bw; Ab[1]=0u; Ab[2]=0u; Ab[3]=0u;
                acc[ot][0] = MFMA(BC16(Ab), BC16(Bc), acc[ot][0]);
                acc[ot][1] = MFMA(BC16(Ab), BC16(Bc), acc[ot][1]);
            }
            __builtin_amdgcn_s_setprio(0);
            convert();
            __syncthreads();                                   // buf (l&1) free; prior stage landed
            stageN(ws + WS_L((l+2)&3), smem + (size_t)(l&1)*65536, tid, 65536);
        }

        // ---- heads: 13 outputs, rows 0..15 of a 32-row tile (3 passes + bias) ----
        f32x16 h6[2];
        __builtin_amdgcn_s_setprio(1);
        #pragma unroll
        for (int k = 0; k < 8; ++k) {
            u32x4 Av = *(const u32x4*)(smem + LDS_HEADS + (col&15)*512 + ((k*32 + hib) ^ sm));
            s16x8 a = BC16(Av);
            h6[0] = MFMA(a, BC16(Bl[0][k]), (k==0) ? zf : h6[0]);
            h6[1] = MFMA(a, BC16(Bl[1][k]), (k==0) ? zf : h6[1]);
        }
        #pragma unroll
        for (int k = 0; k < 8; ++k) {
            const char* rp = smem + LDS_HEADS + (col&15)*512;
            int so = (k*32 + hib) ^ sm;
            u32x4 AvH = *(const u32x4*)(rp + so);
            u32x4 AvL = *(const u32x4*)(rp + 256 + so);
            h6[0] = MFMA(BC16(AvH), BC16(Bh[0][k]), h6[0]);
            h6[1] = MFMA(BC16(AvH), BC16(Bh[1][k]), h6[1]);
            h6[0] = MFMA(BC16(AvL), BC16(Bh[0][k]), h6[0]);
            h6[1] = MFMA(BC16(AvL), BC16(Bh[1][k]), h6[1]);
        }
        {
            u32 bw = (u32)*(const uint16_t*)(smem + LDS_BIAS + (512 + col)*2);
            u32x4 Ab; Ab[0] = hi ? 0u : bw; Ab[1]=0u; Ab[2]=0u; Ab[3]=0u;
            h6[0] = MFMA(BC16(Ab), BC16(Bc), h6[0]);
            h6[1] = MFMA(BC16(Ab), BC16(Bc), h6[1]);
        }
        __builtin_amdgcn_s_setprio(0);

        // ---- t0 + coeff.tb contraction, split across the hi=0/hi=1 lane pair ----
        // hi=0: c[0..3]=t0..3 (rows 0-3), c[4]=t8, c[5]=t9, c[6]=g1, c[7]=g2 (rows 8-11)
        // hi=1: c[0..3]=t4..7 (rows 4-7), c[4]=g3 (row 12)
        #pragma unroll
        for (int pt = 0; pt < 2; ++pt) {
            int p = pb + pt*32 + col;
            if (p < NPTS) {
                const float* tbp = tb + (size_t)p*90;
                f32x16 c = h6[pt];
                const float sixth = 0.16666666666666666f;
                const float third = 0.3333333333333333f;
                float s[9];
                if (hi == 0) {
                    float g1 = c[6], g2 = c[7];
                    s[0] = -g1*third + g2*sixth;
                    s[4] =  g1*sixth - g2*third;
                    s[8] =  g1*sixth + g2*sixth;
                } else {
                    float g3 = c[4];
                    s[0] =  g3*sixth;
                    s[4] =  g3*sixth;
                    s[8] = -g3*third;
                }
                s[1]=s[2]=s[3]=s[5]=s[6]=s[7]=0.f;
                #pragma unroll
                for (int j = 0; j < 4; ++j) {
                    int trow = (hi ? 4 : 0) + j;
                    float cf = c[j];
                    const float* r = tbp + trow*9;
                    f32x4u r0 = *(const f32x4u*)(r);
                    f32x4u r1 = *(const f32x4u*)(r + 4);
                    float r8 = r[8];
                    s[0] += cf*r0.x; s[1] += cf*r0.y; s[2] += cf*r0.z; s[3] += cf*r0.w;
                    s[4] += cf*r1.x; s[5] += cf*r1.y; s[6] += cf*r1.z; s[7] += cf*r1.w;
                    s[8] += cf*r8;
                }
                if (hi == 0) {
                    #pragma unroll
                    for (int j = 4; j < 6; ++j) {
                        int trow = 4 + j;           // t8, t9
                        float cf = c[j];
                        const float* r = tbp + trow*9;
                        f32x4u r0 = *(const f32x4u*)(r);
                        f32x4u r1 = *(const f32x4u*)(r + 4);
                        float r8 = r[8];
                        s[0] += cf*r0.x; s[1] += cf*r0.y; s[2] += cf*r0.z; s[3] += cf*r0.w;
                        s[4] += cf*r1.x; s[5] += cf*r1.y; s[6] += cf*r1.z; s[7] += cf*r1.w;
                        s[8] += cf*r8;
                    }
                }
                #pragma unroll
                for (int j = 0; j < 9; ++j) {  // merge hi0/hi1 partials (pairs share p)
                    u32 uv = __builtin_bit_cast(u32, s[j]);
                    auto rr = __builtin_amdgcn_permlane32_swap(uv, uv, false, false);
                    s[j] = __builtin_bit_cast(float, (u32)rr[0]) + __builtin_bit_cast(float, (u32)rr[1]);
                }
                if (hi == 0) {
                    float* op = out + (size_t)p*9;
                    f32x4u o0, o1;
                    o0.x=s[0]; o0.y=s[1]; o0.z=s[2]; o0.w=s[3];
                    o1.x=s[4]; o1.y=s[5]; o1.z=s[6]; o1.w=s[7];
                    *(f32x4u*)op       = o0;
                    *(f32x4u*)(op + 4) = o1;
                    op[8] = s[8];
                }
            }
        }
    }
    __syncthreads();   // drain in-flight stages before workgroup teardown
}

extern "C" void kernel_launch(void* const* d_in, const int* in_sizes, int n_in,
                              void* d_out, int out_size, void* d_ws, size_t ws_size,
                              hipStream_t stream) {
    (void)in_sizes; (void)n_in; (void)out_size; (void)ws_size;
    char* ws = (char*)d_ws;
    hipLaunchKernelGGL(tbnn_prep, dim3(267), dim3(256), 0, stream,
        (const float*)d_in[2],  (const float*)d_in[3],
        (const float*)d_in[4],  (const float*)d_in[5],
        (const float*)d_in[6],  (const float*)d_in[7],
        (const float*)d_in[8],  (const float*)d_in[9],
        (const float*)d_in[10], (const float*)d_in[11],
        (const float*)d_in[12], (const float*)d_in[13],
        (const float*)d_in[14], (const float*)d_in[15],
        (const float*)d_in[16], (const float*)d_in[17],
        (const float*)d_in[18], (const float*)d_in[19],
        ws);
    (void)hipFuncSetAttribute((const void*)tbnn_main,
                              hipFuncAttributeMaxDynamicSharedMemorySize, LDS_TOTAL);
    hipLaunchKernelGGL(tbnn_main, dim3(NBLKS), dim3(TPB), LDS_TOTAL, stream,
        (const float*)d_in[0], (const float*)d_in[1], ws, (float*)d_out);
}

// Round 4
// 998.086 us; speedup vs baseline: 1.0023x; 1.0023x over previous
//
#include <hip/hip_runtime.h>
#include <stdint.h>

// TBNN fused, split-bf16 (hi+lo) 3-pass MFMA for fp32-grade accuracy.
// prep kernel: pre-splits weights into bf16 hi/lo, pre-swizzled LDS images in d_ws.
// main kernel: 512 thr (8 waves = 2/SIMD from the single resident block; LDS 147KB
// forces 1 block/CU). __launch_bounds__(512,1): minBlocks=1 -> VGPR cap 256 (the
// (512,2) variant capped VGPRs at 128 and spilled 2.2GB to scratch). Each wave owns
// 64 points end-to-end; h stays in registers (cvt_pk + permlane32_swap converts
// MFMA C-layout -> B-layout, hi & lo). Weights roll through a 2x64KB LDS ring via
// global_load_lds. s_setprio(1) around MFMA clusters (T5). 5 barriers/tile.

#define NPTS   1000000
#define TPB    512
#define NBLKS  256
#define NT     ((NPTS + 511) / 512)

typedef uint32_t u32;
typedef __attribute__((ext_vector_type(4)))  u32   u32x4;
typedef __attribute__((ext_vector_type(8)))  short s16x8;
typedef __attribute__((ext_vector_type(16))) float f32x16;
typedef __attribute__((ext_vector_type(4), aligned(4))) float f32x4u;

// ---- workspace layout (prep output, exact LDS images) ----
#define WS_L(s)   ((s)*65536)              // hidden layers 2..5: 128 rows x 512B ([hi 256|lo 256], XOR-swizzled)
#define WS_TAIL   262144                   // heads + W1 + bias, staged as one 16KB block
#define WS_HEADS  262144                   // 16 rows x 512B
#define WS_W1     (262144 + 8192)          // 128 rows x 32B: [Wh(5),b,Wl(5),Wh(5)]
#define WS_BIAS   (262144 + 8192 + 4096)   // [4][128] hidden biases + [32] head biases (bf16)

// ---- LDS layout ----
#define LDS_BUF0   0
#define LDS_BUF1   65536
#define LDS_HEADS  131072
#define LDS_W1     (131072 + 8192)
#define LDS_BIAS   (131072 + 8192 + 4096)
#define LDS_TOTAL  147456

#define MFMA(a,b,c) __builtin_amdgcn_mfma_f32_32x32x16_bf16((a),(b),(c),0,0,0)
#define BC16(v)     __builtin_bit_cast(s16x8, (v))

__device__ __forceinline__ u32 cvtpk(float lo, float hi) {
    u32 r;
    asm("v_cvt_pk_bf16_f32 %0, %1, %2" : "=v"(r) : "v"(lo), "v"(hi));
    return r;
}
__device__ __forceinline__ float lo2f(u32 p){ return __builtin_bit_cast(float, p << 16); }
__device__ __forceinline__ float hi2f(u32 p){ return __builtin_bit_cast(float, p & 0xffff0000u); }
__device__ __forceinline__ uint16_t f2bf(float f) {   // RNE fp32->bf16
    u32 u = __builtin_bit_cast(u32, f);
    return (uint16_t)((u + 0x7fffu + ((u >> 16) & 1u)) >> 16);
}
__device__ __forceinline__ float b2f(uint16_t h){ return __builtin_bit_cast(float, (u32)h << 16); }

// cooperative global->LDS DMA: 512 threads x 16B = 8KB per iteration, linear image copy
__device__ __forceinline__ void stageN(const char* g, char* l, int tid, int nbytes) {
    const int w = tid >> 6, ln = tid & 63;
    const char* gp = g + w*1024 + ln*16;
    char* lp = l + w*1024;                 // wave-uniform LDS base (lane offset is HW-implicit)
    #pragma unroll
    for (int i = 0; i < 8; ++i) {
        if (i*8192 >= nbytes) break;
        __builtin_amdgcn_global_load_lds(
            (const __attribute__((address_space(1))) uint32_t*)(gp + i*8192),
            (__attribute__((address_space(3))) uint32_t*)(lp + i*8192),
            16, 0, 0);
    }
}

// ---------------- prep: split + swizzle weights into ws ----------------
extern "C" __global__ void __launch_bounds__(256)
tbnn_prep(const float* __restrict__ W1, const float* __restrict__ b1,
          const float* __restrict__ W2, const float* __restrict__ b2,
          const float* __restrict__ W3, const float* __restrict__ b3,
          const float* __restrict__ W4, const float* __restrict__ b4,
          const float* __restrict__ W5, const float* __restrict__ b5,
          const float* __restrict__ Wc, const float* __restrict__ bc,
          const float* __restrict__ Wg1,const float* __restrict__ bg1,
          const float* __restrict__ Wg2,const float* __restrict__ bg2,
          const float* __restrict__ Wg3,const float* __restrict__ bg3,
          char* __restrict__ ws)
{
    int idx = blockIdx.x*256 + threadIdx.x;
    if (idx < 65536) {                         // hidden layers 2..5
        int l = idx >> 14, r = idx & 16383, ifc = r >> 7, of = r & 127;
        const float* Wt = (l==0)?W2:(l==1)?W3:(l==2)?W4:W5;
        float w = Wt[ifc*128 + of];
        uint16_t hb = f2bf(w);
        uint16_t lb = f2bf(w - b2f(hb));
        char* row = ws + WS_L(l) + of*512;
        int o = (2*ifc) ^ ((of&7)<<4);         // closed within [0,256)
        *(uint16_t*)(row + o)       = hb;
        *(uint16_t*)(row + 256 + o) = lb;
    } else if (idx < 65536 + 2048) {           // heads: rows 0..9 Wc, 10..12 Wg, 13..15 zero
        int j = idx - 65536, of = j >> 7, ifc = j & 127;
        float v = 0.f;
        if      (of < 10)  v = Wc[ifc*10 + of];
        else if (of == 10) v = Wg1[ifc];
        else if (of == 11) v = Wg2[ifc];
        else if (of == 12) v = Wg3[ifc];
        uint16_t hb = f2bf(v);
        uint16_t lb = f2bf(v - b2f(hb));
        char* row = ws + WS_HEADS + of*512;
        int o = (2*ifc) ^ ((of&7)<<4);
        *(uint16_t*)(row + o)       = hb;
        *(uint16_t*)(row + 256 + o) = lb;
    } else if (idx < 65536 + 2048 + 128) {     // W1 rows: [Wh(5),b,Wl(5),Wh(5)]
        int of = idx - (65536 + 2048);
        uint16_t* dst = (uint16_t*)(ws + WS_W1 + of*32);
        #pragma unroll
        for (int s = 0; s < 5; ++s) {
            float w = W1[s*128 + of];
            uint16_t hb = f2bf(w);
            dst[s]      = hb;
            dst[6 + s]  = f2bf(w - b2f(hb));
            dst[11 + s] = hb;
        }
        dst[5] = f2bf(b1[of]);
    } else if (idx < 65536 + 2048 + 128 + 544) { // bias arrays (bf16)
        int j = idx - (65536 + 2048 + 128);
        float v = 0.f;
        if (j < 512) {
            int l = j >> 7, of = j & 127;
            const float* bt = (l==0)?b2:(l==1)?b3:(l==2)?b4:b5;
            v = bt[of];
        } else {
            int of = j - 512;
            if      (of < 10)  v = bc[of];
            else if (of == 10) v = bg1[0];
            else if (of == 11) v = bg2[0];
            else if (of == 12) v = bg3[0];
        }
        *(uint16_t*)(ws + WS_BIAS + j*2) = f2bf(v);
    }
}

// ---------------- main ----------------
extern "C" __global__ void __launch_bounds__(TPB, 1)
tbnn_main(const float* __restrict__ x, const float* __restrict__ tb,
          const char* __restrict__ ws, float* __restrict__ out)
{
    extern __shared__ char smem[];
    const int tid  = threadIdx.x;
    const int wave = tid >> 6;
    const int lane = tid & 63;
    const int col  = lane & 31;
    const int hi   = lane >> 5;
    const int sm   = (col & 7) << 4;   // read-side swizzle (row&7 == col&7)
    const int hib  = hi * 16;          // byte offset: hi half reads k-slots 8..15

    // initial stages: L2->buf0, L3->buf1, tail (heads+W1+bias)
    stageN(ws + WS_L(0), smem + LDS_BUF0, tid, 65536);
    stageN(ws + WS_L(1), smem + LDS_BUF1, tid, 65536);
    stageN(ws + WS_TAIL, smem + LDS_HEADS, tid, 16384);
    __syncthreads();

    u32x4 Bc; Bc[0] = hi ? 0u : 0x00003F80u; Bc[1]=0u; Bc[2]=0u; Bc[3]=0u; // bias k-step B (1.0 at k=0)
    f32x16 zf;
    #pragma unroll
    for (int i = 0; i < 16; ++i) zf[i] = 0.f;

    for (int t = blockIdx.x; t < NT; t += gridDim.x) {
        const int pb = t*512 + wave*64;

        f32x16 acc[4][2];
        u32x4  Bh[2][8], Bl[2][8];

        // MFMA C-layout -> next-layer B fragments (hi + lo), relu fused
        auto convert = [&]() {
            #pragma unroll
            for (int pt = 0; pt < 2; ++pt)
            #pragma unroll
            for (int ot = 0; ot < 4; ++ot) {
                f32x16 a = acc[ot][pt];
                #pragma unroll
                for (int h2 = 0; h2 < 2; ++h2) {
                    float e0 = fmaxf(a[8*h2+0], 0.f), e1 = fmaxf(a[8*h2+1], 0.f);
                    float e2 = fmaxf(a[8*h2+2], 0.f), e3 = fmaxf(a[8*h2+3], 0.f);
                    float e4 = fmaxf(a[8*h2+4], 0.f), e5 = fmaxf(a[8*h2+5], 0.f);
                    float e6 = fmaxf(a[8*h2+6], 0.f), e7 = fmaxf(a[8*h2+7], 0.f);
                    u32 h01 = cvtpk(e0,e1), h23 = cvtpk(e2,e3);
                    u32 h45 = cvtpk(e4,e5), h67 = cvtpk(e6,e7);
                    u32 l01 = cvtpk(e0 - lo2f(h01), e1 - hi2f(h01));
                    u32 l23 = cvtpk(e2 - lo2f(h23), e3 - hi2f(h23));
                    u32 l45 = cvtpk(e4 - lo2f(h45), e5 - hi2f(h45));
                    u32 l67 = cvtpk(e6 - lo2f(h67), e7 - hi2f(h67));
                    auto sh1 = __builtin_amdgcn_permlane32_swap(h01, h45, false, false);
                    auto sh2 = __builtin_amdgcn_permlane32_swap(h23, h67, false, false);
                    u32x4 fh; fh[0]=sh1[0]; fh[1]=sh2[0]; fh[2]=sh1[1]; fh[3]=sh2[1];
                    Bh[pt][2*ot+h2] = fh;
                    auto sl1 = __builtin_amdgcn_permlane32_swap(l01, l45, false, false);
                    auto sl2 = __builtin_amdgcn_permlane32_swap(l23, l67, false, false);
                    u32x4 fl; fl[0]=sl1[0]; fl[1]=sl2[0]; fl[2]=sl1[1]; fl[3]=sl2[1];
                    Bl[pt][2*ot+h2] = fl;
                }
            }
        };

        { // ---- L1: one K=16 step packs Wh*xh + b + Wl*xh + Wh*xl ----
            u32x4 Bx[2];
            #pragma unroll
            for (int pt = 0; pt < 2; ++pt) {
                int p = pb + pt*32 + col;
                float x0=0.f,x1=0.f,x2=0.f,x3=0.f,x4=0.f;
                if (p < NPTS) {
                    const float* xp = x + (size_t)p*5;
                    f32x4u v = *(const f32x4u*)xp;
                    x0=v.x; x1=v.y; x2=v.z; x3=v.w; x4=xp[4];
                }
                float h0 = lo2f(cvtpk(x0,x0)), l0 = x0 - h0;
                float h1 = lo2f(cvtpk(x1,x1)), l1 = x1 - h1;
                float h2 = lo2f(cvtpk(x2,x2)), l2 = x2 - h2;
                float h3 = lo2f(cvtpk(x3,x3)), l3 = x3 - h3;
                float h4 = lo2f(cvtpk(x4,x4)), l4 = x4 - h4;
                u32x4 B;
                if (hi == 0) {   // k0..7 : [xh0..4, 1, xh0, xh1]
                    B[0] = cvtpk(h0,h1); B[1] = cvtpk(h2,h3);
                    B[2] = cvtpk(h4,1.0f); B[3] = cvtpk(h0,h1);
                } else {         // k8..15: [xh2,xh3,xh4, xl0..4]
                    B[0] = cvtpk(h2,h3); B[1] = cvtpk(h4,l0);
                    B[2] = cvtpk(l1,l2); B[3] = cvtpk(l3,l4);
                }
                Bx[pt] = B;
            }
            __builtin_amdgcn_s_setprio(1);
            #pragma unroll
            for (int ot = 0; ot < 4; ++ot) {
                u32x4 Av = *(const u32x4*)(smem + LDS_W1 + (ot*32+col)*32 + hib);
                s16x8 a = BC16(Av);
                acc[ot][0] = MFMA(a, BC16(Bx[0]), zf);
                acc[ot][1] = MFMA(a, BC16(Bx[1]), zf);
            }
            __builtin_amdgcn_s_setprio(0);
        }
        convert();
        __syncthreads();   // drains rolling stages issued last iteration

        // ---- hidden layers 2..5 (ring: layer l uses buf l&1) ----
        for (int l = 0; l < 4; ++l) {
            const char* wb = smem + (size_t)(l & 1)*65536;
            __builtin_amdgcn_s_setprio(1);
            // P3: Wh * Al  (consumes Bl)
            #pragma unroll
            for (int k = 0; k < 8; ++k)
            #pragma unroll
            for (int ot = 0; ot < 4; ++ot) {
                u32x4 Av = *(const u32x4*)(wb + (ot*32+col)*512 + ((k*32 + hib) ^ sm));
                s16x8 a = BC16(Av);
                acc[ot][0] = MFMA(a, BC16(Bl[0][k]), (k==0) ? zf : acc[ot][0]);
                acc[ot][1] = MFMA(a, BC16(Bl[1][k]), (k==0) ? zf : acc[ot][1]);
            }
            // P1+P2: Wh*Ah + Wl*Ah
            #pragma unroll
            for (int k = 0; k < 8; ++k)
            #pragma unroll
            for (int ot = 0; ot < 4; ++ot) {
                const char* rp = wb + (ot*32+col)*512;
                int so = (k*32 + hib) ^ sm;
                u32x4 AvH = *(const u32x4*)(rp + so);
                u32x4 AvL = *(const u32x4*)(rp + 256 + so);
                acc[ot][0] = MFMA(BC16(AvH), BC16(Bh[0][k]), acc[ot][0]);
                acc[ot][1] = MFMA(BC16(AvH), BC16(Bh[1][k]), acc[ot][1]);
                acc[ot][0] = MFMA(BC16(AvL), BC16(Bh[0][k]), acc[ot][0]);
                acc[ot][1] = MFMA(BC16(AvL), BC16(Bh[1][k]), acc[ot][1]);
            }
            // bias k-step: A = bias column (k_local 0), B = Bc
            #pragma unroll
            for (int ot = 0; ot < 4; ++ot) {
                u32 bw = (u32)*(const uint16_t*)(smem + LDS_BIAS + (l*128 + ot*32 + col)*2);
                u32x4 Ab; Ab[0] = hi ? 0u : bw; Ab[1]=0u; Ab[2]=0u; Ab[3]=0u;
                acc[ot][0] = MFMA(BC16(Ab), BC16(Bc), acc[ot][0]);
                acc[ot][1] = MFMA(BC16(Ab), BC16(Bc), acc[ot][1]);
            }
            __builtin_amdgcn_s_setprio(0);
            convert();
            __syncthreads();                                   // buf (l&1) free; prior stage landed
            stageN(ws + WS_L((l+2)&3), smem + (size_t)(l&1)*65536, tid, 65536);
        }

        // ---- heads: 13 outputs, rows 0..15 of a 32-row tile (3 passes + bias) ----
        f32x16 h6[2];
        __builtin_amdgcn_s_setprio(1);
        #pragma unroll
        for (int k = 0; k < 8; ++k) {
            u32x4 Av = *(const u32x4*)(smem + LDS_HEADS + (col&15)*512 + ((k*32 + hib) ^ sm));
            s16x8 a = BC16(Av);
            h6[0] = MFMA(a, BC16(Bl[0][k]), (k==0) ? zf : h6[0]);
            h6[1] = MFMA(a, BC16(Bl[1][k]), (k==0) ? zf : h6[1]);
        }
        #pragma unroll
        for (int k = 0; k < 8; ++k) {
            const char* rp = smem + LDS_HEADS + (col&15)*512;
            int so = (k*32 + hib) ^ sm;
            u32x4 AvH = *(const u32x4*)(rp + so);
            u32x4 AvL = *(const u32x4*)(rp + 256 + so);
            h6[0] = MFMA(BC16(AvH), BC16(Bh[0][k]), h6[0]);
            h6[1] = MFMA(BC16(AvH), BC16(Bh[1][k]), h6[1]);
            h6[0] = MFMA(BC16(AvL), BC16(Bh[0][k]), h6[0]);
            h6[1] = MFMA(BC16(AvL), BC16(Bh[1][k]), h6[1]);
        }
        {
            u32 bw = (u32)*(const uint16_t*)(smem + LDS_BIAS + (512 + col)*2);
            u32x4 Ab; Ab[0] = hi ? 0u : bw; Ab[1]=0u; Ab[2]=0u; Ab[3]=0u;
            h6[0] = MFMA(BC16(Ab), BC16(Bc), h6[0]);
            h6[1] = MFMA(BC16(Ab), BC16(Bc), h6[1]);
        }
        __builtin_amdgcn_s_setprio(0);

        // ---- t0 + coeff.tb contraction, split across the hi=0/hi=1 lane pair ----
        // hi=0: c[0..3]=t0..3 (rows 0-3), c[4]=t8, c[5]=t9, c[6]=g1, c[7]=g2 (rows 8-11)
        // hi=1: c[0..3]=t4..7 (rows 4-7), c[4]=g3 (row 12)
        #pragma unroll
        for (int pt = 0; pt < 2; ++pt) {
            int p = pb + pt*32 + col;
            if (p < NPTS) {
                const float* tbp = tb + (size_t)p*90;
                f32x16 c = h6[pt];
                const float sixth = 0.16666666666666666f;
                const float third = 0.3333333333333333f;
                float s[9];
                if (hi == 0) {
                    float g1 = c[6], g2 = c[7];
                    s[0] = -g1*third + g2*sixth;
                    s[4] =  g1*sixth - g2*third;
                    s[8] =  g1*sixth + g2*sixth;
                } else {
                    float g3 = c[4];
                    s[0] =  g3*sixth;
                    s[4] =  g3*sixth;
                    s[8] = -g3*third;
                }
                s[1]=s[2]=s[3]=s[5]=s[6]=s[7]=0.f;
                #pragma unroll
                for (int j = 0; j < 4; ++j) {
                    int trow = (hi ? 4 : 0) + j;
                    float cf = c[j];
                    const float* r = tbp + trow*9;
                    f32x4u r0 = *(const f32x4u*)(r);
                    f32x4u r1 = *(const f32x4u*)(r + 4);
                    float r8 = r[8];
                    s[0] += cf*r0.x; s[1] += cf*r0.y; s[2] += cf*r0.z; s[3] += cf*r0.w;
                    s[4] += cf*r1.x; s[5] += cf*r1.y; s[6] += cf*r1.z; s[7] += cf*r1.w;
                    s[8] += cf*r8;
                }
                if (hi == 0) {
                    #pragma unroll
                    for (int j = 4; j < 6; ++j) {
                        int trow = 4 + j;           // t8, t9
                        float cf = c[j];
                        const float* r = tbp + trow*9;
                        f32x4u r0 = *(const f32x4u*)(r);
                        f32x4u r1 = *(const f32x4u*)(r + 4);
                        float r8 = r[8];
                        s[0] += cf*r0.x; s[1] += cf*r0.y; s[2] += cf*r0.z; s[3] += cf*r0.w;
                        s[4] += cf*r1.x; s[5] += cf*r1.y; s[6] += cf*r1.z; s[7] += cf*r1.w;
                        s[8] += cf*r8;
                    }
                }
                #pragma unroll
                for (int j = 0; j < 9; ++j) {  // merge hi0/hi1 partials (pairs share p)
                    u32 uv = __builtin_bit_cast(u32, s[j]);
                    auto rr = __builtin_amdgcn_permlane32_swap(uv, uv, false, false);
                    s[j] = __builtin_bit_cast(float, (u32)rr[0]) + __builtin_bit_cast(float, (u32)rr[1]);
                }
                if (hi == 0) {
                    float* op = out + (size_t)p*9;
                    f32x4u o0, o1;
                    o0.x=s[0]; o0.y=s[1]; o0.z=s[2]; o0.w=s[3];
                    o1.x=s[4]; o1.y=s[5]; o1.z=s[6]; o1.w=s[7];
                    *(f32x4u*)op       = o0;
                    *(f32x4u*)(op + 4) = o1;
                    op[8] = s[8];
                }
            }
        }
    }
    __syncthreads();   // drain in-flight stages before workgroup teardown
}

extern "C" void kernel_launch(void* const* d_in, const int* in_sizes, int n_in,
                              void* d_out, int out_size, void* d_ws, size_t ws_size,
                              hipStream_t stream) {
    (void)in_sizes; (void)n_in; (void)out_size; (void)ws_size;
    char* ws = (char*)d_ws;
    hipLaunchKernelGGL(tbnn_prep, dim3(267), dim3(256), 0, stream,
        (const float*)d_in[2],  (const float*)d_in[3],
        (const float*)d_in[4],  (const float*)d_in[5],
        (const float*)d_in[6],  (const float*)d_in[7],
        (const float*)d_in[8],  (const float*)d_in[9],
        (const float*)d_in[10], (const float*)d_in[11],
        (const float*)d_in[12], (const float*)d_in[13],
        (const float*)d_in[14], (const float*)d_in[15],
        (const float*)d_in[16], (const float*)d_in[17],
        (const float*)d_in[18], (const float*)d_in[19],
        ws);
    (void)hipFuncSetAttribute((const void*)tbnn_main,
                              hipFuncAttributeMaxDynamicSharedMemorySize, LDS_TOTAL);
    hipLaunchKernelGGL(tbnn_main, dim3(NBLKS), dim3(TPB), LDS_TOTAL, stream,
        (const float*)d_in[0], (const float*)d_in[1], ws, (float*)d_out);
}

// Round 5
// 410.256 us; speedup vs baseline: 2.4384x; 2.4328x over previous
//
#include <hip/hip_runtime.h>
#include <stdint.h>

// TBNN fused, split-bf16 (hi+lo) 3-pass MFMA for fp32-grade accuracy.
// Round-5 structure: 32 pts/wave (halves per-wave register state to ~180 so
// 2 waves/SIMD are legal), TPB=256, LDS=80KB exactly -> 2 blocks/CU = 8 waves/CU.
// Each layer's weights split into Wh(32KB)/Wl(32KB) images in two ping-pong LDS
// buffers; phase A = fused P3+P1 (one Wh read -> 2 MFMAs) overlapped with Wl
// staging, phase B = P2+bias+convert overlapped with next Wh staging.

#define NPTS   1000000
#define TPB    256
#define NBLKS  512
#define PTILE  128
#define NT     ((NPTS + PTILE - 1) / PTILE)

typedef uint32_t u32;
typedef __attribute__((ext_vector_type(4)))  u32   u32x4;
typedef __attribute__((ext_vector_type(8)))  short s16x8;
typedef __attribute__((ext_vector_type(16))) float f32x16;
typedef __attribute__((ext_vector_type(4), aligned(4))) float f32x4u;

// ---- workspace layout (prep output, exact LDS images) ----
#define WS_H(l)   ((l)*32768)              // Wh images: 128 rows x 256B, XOR-swizzled
#define WS_Lo(l)  (131072 + (l)*32768)     // Wl images: 128 rows x 256B
#define WS_TAIL   262144                   // heads(8K,512B rows hi|lo) + W1(4K) + bias
#define WS_W1     (WS_TAIL + 8192)
#define WS_BIAS   (WS_TAIL + 12288)

// ---- LDS layout (80KB total) ----
#define LDS_BUFH   0                       // 32KB: current layer Wh
#define LDS_BUFL   32768                   // 32KB: current layer Wl
#define LDS_HEADS  65536                   // 16KB tail
#define LDS_W1     (65536 + 8192)
#define LDS_BIAS   (65536 + 12288)
#define LDS_TOTAL  81920

#define MFMA(a,b,c) __builtin_amdgcn_mfma_f32_32x32x16_bf16((a),(b),(c),0,0,0)
#define BC16(v)     __builtin_bit_cast(s16x8, (v))

__device__ __forceinline__ u32 cvtpk(float lo, float hi) {
    u32 r;
    asm("v_cvt_pk_bf16_f32 %0, %1, %2" : "=v"(r) : "v"(lo), "v"(hi));
    return r;
}
__device__ __forceinline__ float lo2f(u32 p){ return __builtin_bit_cast(float, p << 16); }
__device__ __forceinline__ float hi2f(u32 p){ return __builtin_bit_cast(float, p & 0xffff0000u); }
__device__ __forceinline__ uint16_t f2bf(float f) {   // RNE fp32->bf16
    u32 u = __builtin_bit_cast(u32, f);
    return (uint16_t)((u + 0x7fffu + ((u >> 16) & 1u)) >> 16);
}
__device__ __forceinline__ float b2f(uint16_t h){ return __builtin_bit_cast(float, (u32)h << 16); }

// cooperative global->LDS DMA, 256 threads: 4KB per iteration, linear image copy
__device__ __forceinline__ void stage32(const char* g, char* l, int tid) {
    const int w = tid >> 6, ln = tid & 63;
    const char* gp = g + w*1024 + ln*16;
    char* lp = l + w*1024;                 // wave-uniform LDS base (lane offset HW-implicit)
    #pragma unroll
    for (int i = 0; i < 8; ++i)
        __builtin_amdgcn_global_load_lds(
            (const __attribute__((address_space(1))) uint32_t*)(gp + i*4096),
            (__attribute__((address_space(3))) uint32_t*)(lp + i*4096), 16, 0, 0);
}
__device__ __forceinline__ void stage16(const char* g, char* l, int tid) {
    const int w = tid >> 6, ln = tid & 63;
    const char* gp = g + w*1024 + ln*16;
    char* lp = l + w*1024;
    #pragma unroll
    for (int i = 0; i < 4; ++i)
        __builtin_amdgcn_global_load_lds(
            (const __attribute__((address_space(1))) uint32_t*)(gp + i*4096),
            (__attribute__((address_space(3))) uint32_t*)(lp + i*4096), 16, 0, 0);
}

// ---------------- prep: split + swizzle weights into ws ----------------
extern "C" __global__ void __launch_bounds__(256)
tbnn_prep(const float* __restrict__ W1, const float* __restrict__ b1,
          const float* __restrict__ W2, const float* __restrict__ b2,
          const float* __restrict__ W3, const float* __restrict__ b3,
          const float* __restrict__ W4, const float* __restrict__ b4,
          const float* __restrict__ W5, const float* __restrict__ b5,
          const float* __restrict__ Wc, const float* __restrict__ bc,
          const float* __restrict__ Wg1,const float* __restrict__ bg1,
          const float* __restrict__ Wg2,const float* __restrict__ bg2,
          const float* __restrict__ Wg3,const float* __restrict__ bg3,
          char* __restrict__ ws)
{
    int idx = blockIdx.x*256 + threadIdx.x;
    if (idx < 65536) {                         // hidden layers 2..5 -> Wh/Wl images
        int l = idx >> 14, r = idx & 16383, ifc = r >> 7, of = r & 127;
        const float* Wt = (l==0)?W2:(l==1)?W3:(l==2)?W4:W5;
        float w = Wt[ifc*128 + of];
        uint16_t hb = f2bf(w);
        uint16_t lb = f2bf(w - b2f(hb));
        int o = (2*ifc) ^ ((of&7)<<4);         // closed within [0,256)
        *(uint16_t*)(ws + WS_H(l)  + of*256 + o) = hb;
        *(uint16_t*)(ws + WS_Lo(l) + of*256 + o) = lb;
    } else if (idx < 65536 + 2048) {           // heads: rows 0..9 Wc, 10..12 Wg, 13..15 zero
        int j = idx - 65536, of = j >> 7, ifc = j & 127;
        float v = 0.f;
        if      (of < 10)  v = Wc[ifc*10 + of];
        else if (of == 10) v = Wg1[ifc];
        else if (of == 11) v = Wg2[ifc];
        else if (of == 12) v = Wg3[ifc];
        uint16_t hb = f2bf(v);
        uint16_t lb = f2bf(v - b2f(hb));
        char* row = ws + WS_TAIL + of*512;     // [hi 256 | lo 256]
        int o = (2*ifc) ^ ((of&7)<<4);
        *(uint16_t*)(row + o)       = hb;
        *(uint16_t*)(row + 256 + o) = lb;
    } else if (idx < 65536 + 2048 + 128) {     // W1 rows: [Wh(5),b,Wl(5),Wh(5)]
        int of = idx - (65536 + 2048);
        uint16_t* dst = (uint16_t*)(ws + WS_W1 + of*32);
        #pragma unroll
        for (int s = 0; s < 5; ++s) {
            float w = W1[s*128 + of];
            uint16_t hb = f2bf(w);
            dst[s]      = hb;
            dst[6 + s]  = f2bf(w - b2f(hb));
            dst[11 + s] = hb;
        }
        dst[5] = f2bf(b1[of]);
    } else if (idx < 65536 + 2048 + 128 + 544) { // bias arrays (bf16)
        int j = idx - (65536 + 2048 + 128);
        float v = 0.f;
        if (j < 512) {
            int l = j >> 7, of = j & 127;
            const float* bt = (l==0)?b2:(l==1)?b3:(l==2)?b4:b5;
            v = bt[of];
        } else {
            int of = j - 512;
            if      (of < 10)  v = bc[of];
            else if (of == 10) v = bg1[0];
            else if (of == 11) v = bg2[0];
            else if (of == 12) v = bg3[0];
        }
        *(uint16_t*)(ws + WS_BIAS + j*2) = f2bf(v);
    }
}

// ---------------- main ----------------
extern "C" __global__ void __launch_bounds__(TPB, 2)
tbnn_main(const float* __restrict__ x, const float* __restrict__ tb,
          const char* __restrict__ ws, float* __restrict__ out)
{
    extern __shared__ char smem[];
    const int tid  = threadIdx.x;
    const int wave = tid >> 6;
    const int lane = tid & 63;
    const int col  = lane & 31;
    const int hi   = lane >> 5;
    const int sm   = (col & 7) << 4;   // read-side swizzle (row&7 == col&7)
    const int hib  = hi * 16;          // hi half reads k-slots 8..15

    // prologue: tail (heads+W1+bias) + Wh(L2)
    stage16(ws + WS_TAIL, smem + LDS_HEADS, tid);
    stage32(ws + WS_H(0), smem + LDS_BUFH, tid);
    __syncthreads();

    u32x4 Bc; Bc[0] = hi ? 0u : 0x00003F80u; Bc[1]=0u; Bc[2]=0u; Bc[3]=0u; // bias k-step (1.0 at k=0)
    f32x16 zf;
    #pragma unroll
    for (int i = 0; i < 16; ++i) zf[i] = 0.f;

    for (int t = blockIdx.x; t < NT; t += gridDim.x) {
        const int pb = t*PTILE + wave*32;
        const int p  = pb + col;

        f32x16 acc[4];
        u32x4  Bh[8], Bl[8];

        // MFMA C-layout -> next-layer B fragments (hi + lo), relu fused
        auto convert = [&]() {
            #pragma unroll
            for (int ot = 0; ot < 4; ++ot) {
                f32x16 a = acc[ot];
                #pragma unroll
                for (int h2 = 0; h2 < 2; ++h2) {
                    float e0 = fmaxf(a[8*h2+0], 0.f), e1 = fmaxf(a[8*h2+1], 0.f);
                    float e2 = fmaxf(a[8*h2+2], 0.f), e3 = fmaxf(a[8*h2+3], 0.f);
                    float e4 = fmaxf(a[8*h2+4], 0.f), e5 = fmaxf(a[8*h2+5], 0.f);
                    float e6 = fmaxf(a[8*h2+6], 0.f), e7 = fmaxf(a[8*h2+7], 0.f);
                    u32 h01 = cvtpk(e0,e1), h23 = cvtpk(e2,e3);
                    u32 h45 = cvtpk(e4,e5), h67 = cvtpk(e6,e7);
                    u32 l01 = cvtpk(e0 - lo2f(h01), e1 - hi2f(h01));
                    u32 l23 = cvtpk(e2 - lo2f(h23), e3 - hi2f(h23));
                    u32 l45 = cvtpk(e4 - lo2f(h45), e5 - hi2f(h45));
                    u32 l67 = cvtpk(e6 - lo2f(h67), e7 - hi2f(h67));
                    auto sh1 = __builtin_amdgcn_permlane32_swap(h01, h45, false, false);
                    auto sh2 = __builtin_amdgcn_permlane32_swap(h23, h67, false, false);
                    u32x4 fh; fh[0]=sh1[0]; fh[1]=sh2[0]; fh[2]=sh1[1]; fh[3]=sh2[1];
                    Bh[2*ot+h2] = fh;
                    auto sl1 = __builtin_amdgcn_permlane32_swap(l01, l45, false, false);
                    auto sl2 = __builtin_amdgcn_permlane32_swap(l23, l67, false, false);
                    u32x4 fl; fl[0]=sl1[0]; fl[1]=sl2[0]; fl[2]=sl1[1]; fl[3]=sl2[1];
                    Bl[2*ot+h2] = fl;
                }
            }
        };

        // step 1: stage Wl(L2) (bufL free since prev tile's phase B(3)); L1 compute
        stage32(ws + WS_Lo(0), smem + LDS_BUFL, tid);
        {
            float x0=0.f,x1=0.f,x2=0.f,x3=0.f,x4=0.f;
            if (p < NPTS) {
                const float* xp = x + (size_t)p*5;
                f32x4u v = *(const f32x4u*)xp;
                x0=v.x; x1=v.y; x2=v.z; x3=v.w; x4=xp[4];
            }
            float h0 = lo2f(cvtpk(x0,x0)), l0 = x0 - h0;
            float h1 = lo2f(cvtpk(x1,x1)), l1 = x1 - h1;
            float h2 = lo2f(cvtpk(x2,x2)), l2 = x2 - h2;
            float h3 = lo2f(cvtpk(x3,x3)), l3 = x3 - h3;
            float h4 = lo2f(cvtpk(x4,x4)), l4 = x4 - h4;
            u32x4 Bx;
            if (hi == 0) {   // k0..7 : [xh0..4, 1, xh0, xh1]
                Bx[0] = cvtpk(h0,h1); Bx[1] = cvtpk(h2,h3);
                Bx[2] = cvtpk(h4,1.0f); Bx[3] = cvtpk(h0,h1);
            } else {         // k8..15: [xh2,xh3,xh4, xl0..4]
                Bx[0] = cvtpk(h2,h3); Bx[1] = cvtpk(h4,l0);
                Bx[2] = cvtpk(l1,l2); Bx[3] = cvtpk(l3,l4);
            }
            #pragma unroll
            for (int ot = 0; ot < 4; ++ot) {
                u32x4 Av = *(const u32x4*)(smem + LDS_W1 + (ot*32+col)*32 + hib);
                acc[ot] = MFMA(BC16(Av), BC16(Bx), zf);
            }
        }
        convert();
        __syncthreads();   // Wl(L2) landed; Wh(L2) resident

        // ---- hidden layers 2..5: phase A (P3+P1 from Wh) / phase B (P2 from Wl) ----
        for (int l = 0; l < 4; ++l) {
            // phase A: fused P3+P1 — one Wh read serves two MFMAs
            if (l) stage32(ws + WS_Lo(l), smem + LDS_BUFL, tid);  // l==0 staged in step 1
            __builtin_amdgcn_s_setprio(1);
            #pragma unroll
            for (int k = 0; k < 8; ++k) {
                int so = (k*32 + hib) ^ sm;
                const char* rp = smem + LDS_BUFH + col*256 + so;
                u32x4 A0 = *(const u32x4*)(rp);
                u32x4 A1 = *(const u32x4*)(rp + 32*256);
                u32x4 A2 = *(const u32x4*)(rp + 64*256);
                u32x4 A3 = *(const u32x4*)(rp + 96*256);
                s16x8 bl = BC16(Bl[k]), bh = BC16(Bh[k]);
                acc[0] = MFMA(BC16(A0), bl, (k==0)?zf:acc[0]);
                acc[1] = MFMA(BC16(A1), bl, (k==0)?zf:acc[1]);
                acc[2] = MFMA(BC16(A2), bl, (k==0)?zf:acc[2]);
                acc[3] = MFMA(BC16(A3), bl, (k==0)?zf:acc[3]);
                acc[0] = MFMA(BC16(A0), bh, acc[0]);
                acc[1] = MFMA(BC16(A1), bh, acc[1]);
                acc[2] = MFMA(BC16(A2), bh, acc[2]);
                acc[3] = MFMA(BC16(A3), bh, acc[3]);
            }
            __builtin_amdgcn_s_setprio(0);
            __syncthreads();   // Wl(l) landed; everyone done with Wh(l)

            // phase B: P2 (Wl * Ah) + bias, stage next Wh into bufH
            stage32(ws + WS_H(l==3 ? 0 : l+1), smem + LDS_BUFH, tid);
            __builtin_amdgcn_s_setprio(1);
            #pragma unroll
            for (int k = 0; k < 8; ++k) {
                int so = (k*32 + hib) ^ sm;
                const char* rp = smem + LDS_BUFL + col*256 + so;
                s16x8 bh = BC16(Bh[k]);
                u32x4 A0 = *(const u32x4*)(rp);
                u32x4 A1 = *(const u32x4*)(rp + 32*256);
                u32x4 A2 = *(const u32x4*)(rp + 64*256);
                u32x4 A3 = *(const u32x4*)(rp + 96*256);
                acc[0] = MFMA(BC16(A0), bh, acc[0]);
                acc[1] = MFMA(BC16(A1), bh, acc[1]);
                acc[2] = MFMA(BC16(A2), bh, acc[2]);
                acc[3] = MFMA(BC16(A3), bh, acc[3]);
            }
            #pragma unroll
            for (int ot = 0; ot < 4; ++ot) {   // bias k-step
                u32 bw = (u32)*(const uint16_t*)(smem + LDS_BIAS + (l*128 + ot*32 + col)*2);
                u32x4 Ab; Ab[0] = hi ? 0u : bw; Ab[1]=0u; Ab[2]=0u; Ab[3]=0u;
                acc[ot] = MFMA(BC16(Ab), BC16(Bc), acc[ot]);
            }
            __builtin_amdgcn_s_setprio(0);
            convert();
            __syncthreads();   // next Wh landed; everyone done with Wl(l)
        }

        // ---- heads: 13 outputs, rows 0..15, fused 3-pass + bias (tail resident) ----
        f32x16 h6;
        __builtin_amdgcn_s_setprio(1);
        #pragma unroll
        for (int k = 0; k < 8; ++k) {
            int so = (k*32 + hib) ^ sm;
            const char* rp = smem + LDS_HEADS + (col&15)*512;
            u32x4 AvH = *(const u32x4*)(rp + so);
            u32x4 AvL = *(const u32x4*)(rp + 256 + so);
            h6 = MFMA(BC16(AvH), BC16(Bl[k]), (k==0)?zf:h6);
            h6 = MFMA(BC16(AvH), BC16(Bh[k]), h6);
            h6 = MFMA(BC16(AvL), BC16(Bh[k]), h6);
        }
        {
            u32 bw = (u32)*(const uint16_t*)(smem + LDS_BIAS + (512 + col)*2);
            u32x4 Ab; Ab[0] = hi ? 0u : bw; Ab[1]=0u; Ab[2]=0u; Ab[3]=0u;
            h6 = MFMA(BC16(Ab), BC16(Bc), h6);
        }
        __builtin_amdgcn_s_setprio(0);

        // ---- t0 + coeff.tb contraction, split across the hi=0/hi=1 lane pair ----
        // hi=0: c[0..3]=t0..3, c[4]=t8, c[5]=t9, c[6]=g1, c[7]=g2 ; hi=1: c[0..3]=t4..7, c[4]=g3
        if (p < NPTS) {
            const float* tbp = tb + (size_t)p*90;
            f32x16 c = h6;
            const float sixth = 0.16666666666666666f;
            const float third = 0.3333333333333333f;
            float s[9];
            if (hi == 0) {
                float g1 = c[6], g2 = c[7];
                s[0] = -g1*third + g2*sixth;
                s[4] =  g1*sixth - g2*third;
                s[8] =  g1*sixth + g2*sixth;
            } else {
                float g3 = c[4];
                s[0] =  g3*sixth;
                s[4] =  g3*sixth;
                s[8] = -g3*third;
            }
            s[1]=s[2]=s[3]=s[5]=s[6]=s[7]=0.f;
            #pragma unroll
            for (int j = 0; j < 4; ++j) {
                int trow = (hi ? 4 : 0) + j;
                float cf = c[j];
                const float* r = tbp + trow*9;
                f32x4u r0 = *(const f32x4u*)(r);
                f32x4u r1 = *(const f32x4u*)(r + 4);
                float r8 = r[8];
                s[0] += cf*r0.x; s[1] += cf*r0.y; s[2] += cf*r0.z; s[3] += cf*r0.w;
                s[4] += cf*r1.x; s[5] += cf*r1.y; s[6] += cf*r1.z; s[7] += cf*r1.w;
                s[8] += cf*r8;
            }
            if (hi == 0) {
                #pragma unroll
                for (int j = 4; j < 6; ++j) {
                    int trow = 4 + j;           // t8, t9
                    float cf = c[j];
                    const float* r = tbp + trow*9;
                    f32x4u r0 = *(const f32x4u*)(r);
                    f32x4u r1 = *(const f32x4u*)(r + 4);
                    float r8 = r[8];
                    s[0] += cf*r0.x; s[1] += cf*r0.y; s[2] += cf*r0.z; s[3] += cf*r0.w;
                    s[4] += cf*r1.x; s[5] += cf*r1.y; s[6] += cf*r1.z; s[7] += cf*r1.w;
                    s[8] += cf*r8;
                }
            }
            #pragma unroll
            for (int j = 0; j < 9; ++j) {  // merge hi0/hi1 partials (pairs share p)
                u32 uv = __builtin_bit_cast(u32, s[j]);
                auto rr = __builtin_amdgcn_permlane32_swap(uv, uv, false, false);
                s[j] = __builtin_bit_cast(float, (u32)rr[0]) + __builtin_bit_cast(float, (u32)rr[1]);
            }
            if (hi == 0) {
                float* op = out + (size_t)p*9;
                f32x4u o0, o1;
                o0.x=s[0]; o0.y=s[1]; o0.z=s[2]; o0.w=s[3];
                o1.x=s[4]; o1.y=s[5]; o1.z=s[6]; o1.w=s[7];
                *(f32x4u*)op       = o0;
                *(f32x4u*)(op + 4) = o1;
                op[8] = s[8];
            }
        }
    }
    __syncthreads();   // drain in-flight stages before workgroup teardown
}

extern "C" void kernel_launch(void* const* d_in, const int* in_sizes, int n_in,
                              void* d_out, int out_size, void* d_ws, size_t ws_size,
                              hipStream_t stream) {
    (void)in_sizes; (void)n_in; (void)out_size; (void)ws_size;
    char* ws = (char*)d_ws;
    hipLaunchKernelGGL(tbnn_prep, dim3(267), dim3(256), 0, stream,
        (const float*)d_in[2],  (const float*)d_in[3],
        (const float*)d_in[4],  (const float*)d_in[5],
        (const float*)d_in[6],  (const float*)d_in[7],
        (const float*)d_in[8],  (const float*)d_in[9],
        (const float*)d_in[10], (const float*)d_in[11],
        (const float*)d_in[12], (const float*)d_in[13],
        (const float*)d_in[14], (const float*)d_in[15],
        (const float*)d_in[16], (const float*)d_in[17],
        (const float*)d_in[18], (const float*)d_in[19],
        ws);
    (void)hipFuncSetAttribute((const void*)tbnn_main,
                              hipFuncAttributeMaxDynamicSharedMemorySize, LDS_TOTAL);
    hipLaunchKernelGGL(tbnn_main, dim3(NBLKS), dim3(TPB), LDS_TOTAL, stream,
        (const float*)d_in[0], (const float*)d_in[1], ws, (float*)d_out);
}